// Round 3
// baseline (26.433 us; speedup 1.0000x reference)
//
#include <hip/hip_runtime.h>

constexpr int NCLS = 16;
constexpr int NG   = 50;
constexpr int CH   = 21;           // 5 + NCLS
constexpr int N0 = 16384, N1 = 4096, N2 = 1024;
constexpr int NTOT    = N0 + N1 + N2;    // 21504
constexpr int APB     = 1024;            // anchors per block (4 per thread)
constexpr int CHUNKS  = NTOT / APB;      // 21 (16 + 4 + 1, each block inside one level)
constexpr float EPSF  = 1e-8f;
constexpr int IMAX = 0x7fffffff;

__global__ __launch_bounds__(256) void dpsv_main_kernel(
    const float* __restrict__ in0,
    const float* __restrict__ in1,
    const float* __restrict__ in2,
    const float* __restrict__ labels,
    float* __restrict__ ws, int nb)
{
    const int tid   = threadIdx.x;
    const int b     = blockIdx.x / CHUNKS;
    const int chunk = blockIdx.x % CHUNKS;

    // ---- stage labels for this batch ----
    __shared__ float lab[5 * NG];
    if (tid < 5 * NG) lab[tid] = labels[b * 5 * NG + tid];

    // ---- level decode (block-uniform: chunk boundaries align with levels) ----
    const float* basep; int Wlog, HW; float s; int hw0;
    if (chunk < 16)      { basep = in0; Wlog = 7; HW = N0; s = 8.f;  hw0 = chunk * APB; }
    else if (chunk < 20) { basep = in1; Wlog = 6; HW = N1; s = 16.f; hw0 = (chunk - 16) * APB; }
    else                 { basep = in2; Wlog = 5; HW = N2; s = 32.f; hw0 = 0; }

    const int hw = hw0 + tid * 4;             // 4 consecutive anchors, same row
    const int x0 = hw & ((1 << Wlog) - 1);
    const int y  = hw >> Wlog;
    const float fx0 = (float)x0, fy = (float)y;
    const float cx0 = (fx0 + 0.5f) * s;
    const float cy  = (fy + 0.5f) * s;
    const float r   = 0.5f * s;

    // ---- per-block GT compaction (y-band cull over rows this block covers) ----
    const int y_min = hw0 >> Wlog;
    const int y_max = (hw0 + APB - 1) >> Wlog;
    const float cyLo = ((float)y_min + 0.5f) * s - r;
    const float cyHi = ((float)y_max + 0.5f) * s + r;

    __shared__ int cnt;
    __shared__ float cgx[NG], cgy[NG];
    __shared__ int   cgi[NG];
    if (tid == 0) cnt = 0;
    __syncthreads();
    if (tid < NG) {
        float gx = lab[tid * 5 + 0];
        float gy = lab[tid * 5 + 1];
        if (gy > cyLo && gy < cyHi) {
            int i = atomicAdd(&cnt, 1);
            cgx[i] = gx; cgy[i] = gy; cgi[i] = tid;
        }
    }
    __syncthreads();
    const int ng = cnt;

    // ---- matching: lowest GT index whose center-region contains each anchor ----
    int m0 = IMAX, m1 = IMAX, m2 = IMAX, m3 = IMAX;
    for (int j = 0; j < ng; ++j) {
        float gx = cgx[j], gy = cgy[j];
        int gi = cgi[j];
        bool yok = fabsf(cy - gy) < r;
        float d = cx0 - gx;
        m0 = min(m0, (yok && fabsf(d)           < r) ? gi : IMAX);
        m1 = min(m1, (yok && fabsf(d + s)       < r) ? gi : IMAX);
        m2 = min(m2, (yok && fabsf(d + 2.f * s) < r) ? gi : IMAX);
        m3 = min(m3, (yok && fabsf(d + 3.f * s) < r) ? gi : IMAX);
    }

    // ---- obj term (all anchors, vectorized load + fast log) ----
    const float* chbase = basep + (size_t)(b * CH) * HW;
    const float4 o4 = *(const float4*)(chbase + 4 * HW + hw);
    const float ov[4] = {o4.x, o4.y, o4.z, o4.w};
    const int   mm[4] = {m0, m1, m2, m3};

    float loss_part = 0.f;
    float v0 = 0.f, v1 = 0.f, v2 = 0.f, v3 = 0.f;

    #pragma unroll
    for (int k = 0; k < 4; ++k) {
        const bool fg = (mm[k] != IMAX);
        loss_part += fg ? (-1000.f * __logf(ov[k] + EPSF))
                        : (-__logf(1.f - ov[k] + EPSF));
        if (fg) {
            const float* lg = &lab[mm[k] * 5];
            const float* chp = chbase + hw + k;
            float xp = (chp[0]  + fx0 + (float)k) * s;
            float yp = (chp[HW] + fy) * s;
            v0 += fabsf((lg[0] - xp) * (1.f / 1024.f));
            v1 += fabsf((lg[1] - yp) * (1.f / 1024.f));
            v2 += fabsf(lg[2] - chp[2 * HW]) * 10.f;
            v3 += fabsf(lg[3] - chp[3 * HW]) * 10.f;
            int ci = (int)lg[4];
            float cls_sum = 0.f;
            #pragma unroll
            for (int c = 0; c < NCLS; ++c) {
                float pc  = chp[(5 + c) * HW];
                float lp  = fmaxf(__logf(pc), -100.f);
                float l1p = fmaxf(__logf(1.f - pc), -100.f);
                cls_sum += (c == ci) ? -lp : -l1p;
            }
            loss_part += 500.f * cls_sum;
        }
    }

    // ---- reduction: wave shuffle -> LDS -> per-block partial store (SoA) ----
    float vals[5] = {loss_part, v0, v1, v2, v3};
    #pragma unroll
    for (int k = 0; k < 5; ++k) {
        float v = vals[k];
        #pragma unroll
        for (int off = 32; off > 0; off >>= 1)
            v += __shfl_xor(v, off, 64);
        vals[k] = v;
    }
    __shared__ float red[4][5];
    const int wave = tid >> 6;
    const int lane = tid & 63;
    if (lane == 0) {
        #pragma unroll
        for (int k = 0; k < 5; ++k) red[wave][k] = vals[k];
    }
    __syncthreads();
    if (tid < 5) {
        ws[tid * nb + blockIdx.x] =
            red[0][tid] + red[1][tid] + red[2][tid] + red[3][tid];
    }
}

__global__ __launch_bounds__(256) void dpsv_reduce_kernel(
    const float* __restrict__ ws, float* __restrict__ out, int nb)
{
    const int tid = threadIdx.x;
    float acc[5] = {0.f, 0.f, 0.f, 0.f, 0.f};
    for (int i = tid; i < nb; i += 256) {
        #pragma unroll
        for (int k = 0; k < 5; ++k) acc[k] += ws[k * nb + i];
    }
    #pragma unroll
    for (int k = 0; k < 5; ++k) {
        float v = acc[k];
        #pragma unroll
        for (int off = 32; off > 0; off >>= 1)
            v += __shfl_xor(v, off, 64);
        acc[k] = v;
    }
    __shared__ float red[4][5];
    const int wave = tid >> 6;
    const int lane = tid & 63;
    if (lane == 0) {
        #pragma unroll
        for (int k = 0; k < 5; ++k) red[wave][k] = acc[k];
    }
    __syncthreads();
    if (tid == 0) {
        float t[5];
        #pragma unroll
        for (int k = 0; k < 5; ++k)
            t[k] = red[0][k] + red[1][k] + red[2][k] + red[3][k];
        out[0] = t[0] + 10000.f * (t[1] + t[2] + t[3] + t[4]);
        out[1] = t[1];
        out[2] = t[2];
        out[3] = t[3];
        out[4] = t[4];
    }
}

extern "C" void kernel_launch(void* const* d_in, const int* in_sizes, int n_in,
                              void* d_out, int out_size, void* d_ws, size_t ws_size,
                              hipStream_t stream) {
    const float* in0    = (const float*)d_in[0];
    const float* in1    = (const float*)d_in[1];
    const float* in2    = (const float*)d_in[2];
    const float* labels = (const float*)d_in[3];
    float* out = (float*)d_out;
    float* ws  = (float*)d_ws;

    const int B  = in_sizes[3] / (5 * NG);   // 32
    const int nb = B * CHUNKS;               // 672 partial rows (SoA: 5*672 floats)

    dpsv_main_kernel<<<nb, 256, 0, stream>>>(in0, in1, in2, labels, ws, nb);
    dpsv_reduce_kernel<<<1, 256, 0, stream>>>(ws, out, nb);
}

// Round 4
// 20.927 us; speedup vs baseline: 1.2631x; 1.2631x over previous
//
#include <hip/hip_runtime.h>

constexpr int NCLS = 16;
constexpr int NG   = 50;
constexpr int CH   = 21;           // 5 + NCLS
constexpr int N0 = 16384, N1 = 4096, N2 = 1024;
constexpr int NTOT   = N0 + N1 + N2;   // 21504
constexpr int CHUNKS = NTOT / 256;     // 84 (each block fully inside one level)
constexpr float EPSF = 1e-8f;
constexpr int IMAX = 0x7fffffff;

__global__ __launch_bounds__(256) void dpsv_main_kernel(
    const float* __restrict__ in0,
    const float* __restrict__ in1,
    const float* __restrict__ in2,
    const float* __restrict__ labels,
    float* __restrict__ ws, int nb)
{
    const int tid   = threadIdx.x;
    const int b     = blockIdx.x / CHUNKS;
    const int chunk = blockIdx.x % CHUNKS;
    const int p     = chunk * 256 + tid;

    // ---- level decode (block-uniform: 16384 and 4096 are multiples of 256) ----
    const float* basep; int hw, Wlog, HW; float s; int hw0;
    if (p < N0)           { basep = in0; hw = p;           Wlog = 7; HW = N0; s = 8.f;  hw0 = chunk * 256; }
    else if (p < N0 + N1) { basep = in1; hw = p - N0;      Wlog = 6; HW = N1; s = 16.f; hw0 = chunk * 256 - N0; }
    else                  { basep = in2; hw = p - N0 - N1; Wlog = 5; HW = N2; s = 32.f; hw0 = chunk * 256 - N0 - N1; }
    const int x = hw & ((1 << Wlog) - 1);
    const int y = hw >> Wlog;
    const float fx = (float)x, fy = (float)y;
    const float cx = (fx + 0.5f) * s;
    const float cy = (fy + 0.5f) * s;
    const float r  = 0.5f * s;

    const float* ch = basep + (size_t)(b * CH) * HW + hw;

    // issue the obj load NOW so its latency hides under staging + cull + match
    const float obj = ch[4 * HW];

    // ---- stage labels for this batch ----
    __shared__ float lab[5 * NG];
    if (tid < 5 * NG) lab[tid] = labels[b * 5 * NG + tid];

    // ---- per-block GT compaction (y-band cull; block spans full rows) ----
    const int y_min = hw0 >> Wlog;
    const int y_max = (hw0 + 255) >> Wlog;
    const float cyLo = ((float)y_min + 0.5f) * s - r;
    const float cyHi = ((float)y_max + 0.5f) * s + r;

    __shared__ int cnt;
    __shared__ float cgx[NG], cgy[NG];
    __shared__ int   cgi[NG];
    if (tid == 0) cnt = 0;
    __syncthreads();
    if (tid < NG) {
        float gx = lab[tid * 5 + 0];
        float gy = lab[tid * 5 + 1];
        if (gy > cyLo && gy < cyHi) {
            int i = atomicAdd(&cnt, 1);
            cgx[i] = gx; cgy[i] = gy; cgi[i] = tid;
        }
    }
    __syncthreads();
    const int ng = cnt;

    // ---- matching: lowest GT index whose center-region contains (cx,cy) ----
    int matched = IMAX;
    for (int j = 0; j < ng; ++j) {
        bool inr = (fabsf(cx - cgx[j]) < r) && (fabsf(cy - cgy[j]) < r);
        matched = min(matched, inr ? cgi[j] : IMAX);
    }
    const bool fg = (matched != IMAX);

    // ---- obj term (all anchors; fast hw log) ----
    float loss_part = fg ? (-1000.f * __logf(obj + EPSF))
                         : (-__logf(1.f - obj + EPSF));
    float v0 = 0.f, v1 = 0.f, v2 = 0.f, v3 = 0.f;

    // ---- vec + cls terms (fg anchors only; ~0.7% of lanes) ----
    if (fg) {
        const float* lg = &lab[matched * 5];
        float xp = (ch[0]  + fx) * s;
        float yp = (ch[HW] + fy) * s;
        v0 = fabsf((lg[0] - xp) * (1.f / 1024.f));
        v1 = fabsf((lg[1] - yp) * (1.f / 1024.f));
        v2 = fabsf(lg[2] - ch[2 * HW]) * 10.f;
        v3 = fabsf(lg[3] - ch[3 * HW]) * 10.f;
        int ci = (int)lg[4];
        float cls_sum = 0.f;
        #pragma unroll
        for (int c = 0; c < NCLS; ++c) {
            float pc  = ch[(5 + c) * HW];
            float lp  = fmaxf(__logf(pc), -100.f);
            float l1p = fmaxf(__logf(1.f - pc), -100.f);
            cls_sum += (c == ci) ? -lp : -l1p;
        }
        loss_part += 500.f * cls_sum;
    }

    // ---- reduction: wave shuffle -> LDS -> per-block partial store (SoA) ----
    // loss_part: always reduced. v0..v3: nonzero only if some lane is fg
    // (wave-uniform ballot) -> skip 24 shuffle-adds in >99% of waves.
    float vals[5] = {loss_part, v0, v1, v2, v3};
    {
        float v = vals[0];
        #pragma unroll
        for (int off = 32; off > 0; off >>= 1)
            v += __shfl_xor(v, off, 64);
        vals[0] = v;
    }
    if (__ballot(fg) != 0ull) {
        #pragma unroll
        for (int k = 1; k < 5; ++k) {
            float v = vals[k];
            #pragma unroll
            for (int off = 32; off > 0; off >>= 1)
                v += __shfl_xor(v, off, 64);
            vals[k] = v;
        }
    }
    __shared__ float red[4][5];
    const int wave = tid >> 6;
    const int lane = tid & 63;
    if (lane == 0) {
        #pragma unroll
        for (int k = 0; k < 5; ++k) red[wave][k] = vals[k];
    }
    __syncthreads();
    if (tid < 5) {
        ws[tid * nb + blockIdx.x] =
            red[0][tid] + red[1][tid] + red[2][tid] + red[3][tid];
    }
}

__global__ __launch_bounds__(256) void dpsv_reduce_kernel(
    const float* __restrict__ ws, float* __restrict__ out, int nb)
{
    const int tid = threadIdx.x;
    float acc[5] = {0.f, 0.f, 0.f, 0.f, 0.f};
    for (int i = tid; i < nb; i += 256) {
        #pragma unroll
        for (int k = 0; k < 5; ++k) acc[k] += ws[k * nb + i];
    }
    #pragma unroll
    for (int k = 0; k < 5; ++k) {
        float v = acc[k];
        #pragma unroll
        for (int off = 32; off > 0; off >>= 1)
            v += __shfl_xor(v, off, 64);
        acc[k] = v;
    }
    __shared__ float red[4][5];
    const int wave = tid >> 6;
    const int lane = tid & 63;
    if (lane == 0) {
        #pragma unroll
        for (int k = 0; k < 5; ++k) red[wave][k] = acc[k];
    }
    __syncthreads();
    if (tid == 0) {
        float t[5];
        #pragma unroll
        for (int k = 0; k < 5; ++k)
            t[k] = red[0][k] + red[1][k] + red[2][k] + red[3][k];
        out[0] = t[0] + 10000.f * (t[1] + t[2] + t[3] + t[4]);
        out[1] = t[1];
        out[2] = t[2];
        out[3] = t[3];
        out[4] = t[4];
    }
}

extern "C" void kernel_launch(void* const* d_in, const int* in_sizes, int n_in,
                              void* d_out, int out_size, void* d_ws, size_t ws_size,
                              hipStream_t stream) {
    const float* in0    = (const float*)d_in[0];
    const float* in1    = (const float*)d_in[1];
    const float* in2    = (const float*)d_in[2];
    const float* labels = (const float*)d_in[3];
    float* out = (float*)d_out;
    float* ws  = (float*)d_ws;

    const int B  = in_sizes[3] / (5 * NG);   // 32
    const int nb = B * CHUNKS;               // 2688 partial rows (SoA in ws)

    dpsv_main_kernel<<<nb, 256, 0, stream>>>(in0, in1, in2, labels, ws, nb);
    dpsv_reduce_kernel<<<1, 256, 0, stream>>>(ws, out, nb);
}